// Round 7
// baseline (26.724 us; speedup 1.0000x reference)
//
#include <hip/hip_runtime.h>
#include <math.h>

// heatmap [64,17,128,128] f32, targets [64,17,3] f32 (x, y, visible)
constexpr int Hc  = 128;
constexpr int Wc  = 128;
constexpr int HWc = Hc * Wc;        // 16384
constexpr int NBK = 64 * 17;        // 1088

constexpr float E2_1 = 0.13533528323661270f;               // e^-2
constexpr float E2_4 = 3.3546262790251185e-4f;             // e^-8
constexpr float S1F  = 1.0f + 2.0f * E2_1 + 2.0f * E2_4;   // 1D kernel sum
constexpr float INVN = 1.0f / (S1F * S1F);                 // 1/k2.sum()

__device__ __forceinline__ float gfac(int d) {   // e^{-2 d^2}, |d|<=2
    const int a = d < 0 ? -d : d;
    return a == 0 ? 1.0f : (a == 1 ? E2_1 : E2_4);
}

// Single pass: one 256-thread block per (b,k) row.
//  - streams the full 16 KB row (16x float4/thread, coalesced) -> sum(exp(x))
//    (no max subtraction: inputs are N(0,1), f32 range ample; matches ref)
//  - lanes 0..24 gather the 5x5 Gaussian window (L1/L2-resident re-read)
//  - wave 1 redundantly computes the global n_vis from targets (13 KB,
//    L2-resident; bit-identical in every block)
//  - block leader: lse = log(S), closed-form window constants, and ONE
//    device-scope atomicAdd(out, per*vis/n_vis). No fences, no counters:
//    d_out is re-zeroed by a 4-byte memset node at the start of each call.
__global__ __launch_bounds__(256) void kl_one(const float* __restrict__ hm,
                                              const float* __restrict__ tg,
                                              float* __restrict__ out) {
    const int bk   = blockIdx.x;
    const int tid  = threadIdx.x;
    const int lane = tid & 63;
    const int wave = tid >> 6;

    const float4* __restrict__ base4 =
        reinterpret_cast<const float4*>(hm + (size_t)bk * HWc);

    // ---- streaming exp-sum over the whole row ----
    float s0 = 0.f, s1 = 0.f, s2 = 0.f, s3 = 0.f;
#pragma unroll
    for (int c = 0; c < 16; ++c) {
        const float4 v = base4[c * 256 + tid];
        s0 += __expf(v.x); s1 += __expf(v.y);
        s2 += __expf(v.z); s3 += __expf(v.w);
    }
    float s = (s0 + s1) + (s2 + s3);

    // ---- Gaussian-window dot product (lanes 0..24 of wave 0) ----
    float gh = 0.f;
    if (tid < 25) {
        const int dy = tid / 5 - 2;
        const int dx = tid % 5 - 2;
        const int tx = __float2int_rn(tg[bk * 3 + 0]) + dx;
        const int ty = __float2int_rn(tg[bk * 3 + 1]) + dy;
        if (tx >= 0 && tx < Wc && ty >= 0 && ty < Hc)
            gh = gfac(dx) * gfac(dy) * INVN * hm[(size_t)bk * HWc + ty * Wc + tx];
    }

    // ---- global n_vis from targets (wave 1; identical in every block) ----
    float nv = 0.f;
    if (wave == 1) {
#pragma unroll
        for (int i = 0; i < NBK / 64; ++i)
            nv += (__float2int_rn(tg[3 * (lane + 64 * i) + 2]) > 0) ? 1.f : 0.f;
    }

#pragma unroll
    for (int off = 32; off; off >>= 1) {
        s  += __shfl_xor(s,  off);
        gh += __shfl_xor(gh, off);
        nv += __shfl_xor(nv, off);
    }

    __shared__ float ss[4];
    __shared__ float sG, sNV;
    if (lane == 0) {
        ss[wave] = s;
        if (wave == 0) sG  = gh;
        if (wave == 1) sNV = nv;
    }
    __syncthreads();

    if (tid == 0) {
        const int vis = __float2int_rn(tg[bk * 3 + 2]) > 0;
        if (vis) {
            const float S   = (ss[0] + ss[1]) + (ss[2] + ss[3]);
            const float lse = __logf(S);
            const int tx = __float2int_rn(tg[bk * 3 + 0]);
            const int ty = __float2int_rn(tg[bk * 3 + 1]);

            const float LOGN = 2.0f * __logf(S1F);   // log(k2.sum())
            float cg = 0.f, cglg = 0.f;
#pragma unroll
            for (int w = 0; w < 25; ++w) {
                const int dy = w / 5 - 2;
                const int dx = w % 5 - 2;
                const int x = tx + dx, y = ty + dy;
                if (x >= 0 && x < Wc && y >= 0 && y < Hc) {
                    const float g = gfac(dx) * gfac(dy) * INVN;
                    cg   += g;
                    cglg += g * (-2.f * (float)(dx * dx + dy * dy) - LOGN);
                }
            }
            const float per = cglg - sG + lse * cg;
            atomicAdd(out, per / fmaxf(sNV, 1.f));
        }
    }
}

extern "C" void kernel_launch(void* const* d_in, const int* in_sizes, int n_in,
                              void* d_out, int out_size, void* d_ws, size_t ws_size,
                              hipStream_t stream) {
    const float* heatmap = (const float*)d_in[0];
    const float* targets = (const float*)d_in[1];
    float* out = (float*)d_out;

    hipMemsetAsync(out, 0, sizeof(float), stream);   // re-zero the accumulator
    kl_one<<<NBK, 256, 0, stream>>>(heatmap, targets, out);
}

// Round 9
// 16.725 us; speedup vs baseline: 1.5979x; 1.5979x over previous
//
#include <hip/hip_runtime.h>
#include <math.h>

// heatmap [64,17,128,128] f32, targets [64,17,3] f32 (x, y, visible)
constexpr int Hc     = 128;
constexpr int Wc     = 128;
constexpr int HWc    = Hc * Wc;          // 16384
constexpr int NBK    = 64 * 17;          // 1088
constexpr int NCHUNK = 4;                // chunks per (b,k) row
constexpr int CHUNK  = HWc / NCHUNK;     // 4096 elements = 32 image rows
constexpr int NBLK   = NBK * NCHUNK;     // 4352 blocks

constexpr float E2_1 = 0.13533528323661270f;               // e^-2
constexpr float E2_4 = 3.3546262790251185e-4f;             // e^-8
constexpr float S1F  = 1.0f + 2.0f * E2_1 + 2.0f * E2_4;   // 1D kernel sum
constexpr float INVN = 1.0f / (S1F * S1F);                 // 1/k2.sum()

typedef float floatx4 __attribute__((ext_vector_type(4)));  // native vec for nt-load

__device__ __forceinline__ float gfac(int d) {   // e^{-2 d^2}, |d|<=2
    const int a = d < 0 ? -d : d;
    return a == 0 ? 1.0f : (a == 1 ? E2_1 : E2_4);
}

// Kernel 1 (R4 structure, best measured): one block per (bk, chunk).
// Streaming loads are NON-TEMPORAL (global_load_dwordx4 ... nt): heatmap is
// read exactly once, skip L2/LLC allocation on the way through.
__global__ __launch_bounds__(256) void kl_chunk(const float* __restrict__ hm,
                                                const float* __restrict__ tg,
                                                float* __restrict__ part) {
    const int bx    = blockIdx.x;
    const int bk    = bx >> 2;
    const int chunk = bx & 3;
    const int tid   = threadIdx.x;

    const floatx4* __restrict__ base4 =
        reinterpret_cast<const floatx4*>(hm + (size_t)bk * HWc + (size_t)chunk * CHUNK);

    float s0 = 0.f, s1 = 0.f, s2 = 0.f, s3 = 0.f;
#pragma unroll
    for (int c = 0; c < 4; ++c) {
        const floatx4 v = __builtin_nontemporal_load(&base4[c * 256 + tid]);
        s0 += __expf(v.x); s1 += __expf(v.y);
        s2 += __expf(v.z); s3 += __expf(v.w);
    }
    float s = (s0 + s1) + (s2 + s3);

    // Gaussian-window partial for rows inside this chunk
    float gh = 0.f;
    if (tid < 25) {
        const int dy = tid / 5 - 2;
        const int dx = tid % 5 - 2;
        const int tx = __float2int_rn(tg[bk * 3 + 0]) + dx;
        const int ty = __float2int_rn(tg[bk * 3 + 1]) + dy;
        const int r0 = chunk * (Hc / NCHUNK);
        if (tx >= 0 && tx < Wc && ty >= r0 && ty < r0 + Hc / NCHUNK)
            gh = gfac(dx) * gfac(dy) * INVN * hm[(size_t)bk * HWc + ty * Wc + tx];
    }

#pragma unroll
    for (int off = 32; off; off >>= 1) s += __shfl_xor(s, off);
#pragma unroll
    for (int off = 16; off; off >>= 1) gh += __shfl_xor(gh, off);

    __shared__ float ss[4];
    const int wave = tid >> 6;
    if ((tid & 63) == 0) ss[wave] = s;
    __syncthreads();
    if (tid == 0) {
        part[bx]        = ss[0] + ss[1] + ss[2] + ss[3];
        part[NBLK + bx] = gh;   // gh fully reduced within wave 0
    }
}

// Kernel 2: single 1024-thread block (16 waves). Per bk: combine 4 chunk
// exp-sums -> lse, closed-form window constants, vis-weighted batchmean.
__global__ __launch_bounds__(1024) void kl_final(const float* __restrict__ part,
                                                 const float* __restrict__ tg,
                                                 float* __restrict__ out) {
    const int tid = threadIdx.x;
    const float LOGN = 2.0f * __logf(S1F);   // log(k2.sum())

    float acc = 0.f, nv = 0.f;
    for (int i = tid; i < NBK; i += 1024) {
        const float4 sv = *reinterpret_cast<const float4*>(part + 4 * i);
        const float4 gv = *reinterpret_cast<const float4*>(part + NBLK + 4 * i);
        const float S   = (sv.x + sv.y) + (sv.z + sv.w);
        const float gh  = (gv.x + gv.y) + (gv.z + gv.w);
        const float lse = __logf(S);

        const int tx  = __float2int_rn(tg[3 * i + 0]);
        const int ty  = __float2int_rn(tg[3 * i + 1]);
        const int vis = __float2int_rn(tg[3 * i + 2]) > 0;

        float cg = 0.f, cglg = 0.f;
#pragma unroll
        for (int w = 0; w < 25; ++w) {
            const int dy = w / 5 - 2;
            const int dx = w % 5 - 2;
            const int x = tx + dx, y = ty + dy;
            if (x >= 0 && x < Wc && y >= 0 && y < Hc) {
                const float g = gfac(dx) * gfac(dy) * INVN;
                cg   += g;
                cglg += g * (-2.f * (float)(dx * dx + dy * dy) - LOGN);
            }
        }
        const float per = cglg - gh + lse * cg;
        acc += vis ? per : 0.f;
        nv  += vis ? 1.f : 0.f;
    }

#pragma unroll
    for (int off = 32; off; off >>= 1) {
        acc += __shfl_xor(acc, off);
        nv  += __shfl_xor(nv,  off);
    }
    __shared__ float sa[16], sn[16];
    const int wave = tid >> 6;
    if ((tid & 63) == 0) { sa[wave] = acc; sn[wave] = nv; }
    __syncthreads();
    if (tid == 0) {
        float a = 0.f, n = 0.f;
#pragma unroll
        for (int w = 0; w < 16; ++w) { a += sa[w]; n += sn[w]; }
        out[0] = a / fmaxf(n, 1.f);
    }
}

extern "C" void kernel_launch(void* const* d_in, const int* in_sizes, int n_in,
                              void* d_out, int out_size, void* d_ws, size_t ws_size,
                              hipStream_t stream) {
    const float* heatmap = (const float*)d_in[0];
    const float* targets = (const float*)d_in[1];
    float* part = (float*)d_ws;
    float* out  = (float*)d_out;

    kl_chunk<<<NBLK, 256, 0, stream>>>(heatmap, targets, part);
    kl_final<<<1, 1024, 0, stream>>>(part, targets, out);
}